// Round 1
// 495.768 us; speedup vs baseline: 1.1446x; 1.1446x over previous
//
#include <hip/hip_runtime.h>
#include <hip/hip_fp16.h>
#include <cstdint>
#include <cstddef>

#define SLOPE 0.2f
#define EPSV 1e-10f
#define NPART 8

#define DOT4(F, Q) ((F).x*(Q).x + (F).y*(Q).y + (F).z*(Q).z + (F).w*(Q).w)

__device__ __forceinline__ float h2_as_float(__half2 v) {
  union { __half2 h; float f; } u; u.h = v; return u.f;
}
__device__ __forceinline__ __half2 float_as_h2(float v) {
  union { float f; __half2 h; } u; u.f = v; return u.h;
}

// K0: Qe[h][k] = sum_t (q[h][2t]+q[h][2t+1]) * We[16h+t][k];  cb[h] likewise with be
__global__ void prep_qe(const float* __restrict__ We, const float* __restrict__ be,
                        const float* __restrict__ query, float* __restrict__ Qe,
                        float* __restrict__ cb) {
  int tid = threadIdx.x;  // 64 threads
  int h = tid >> 4, k = tid & 15;
  float acc = 0.f;
  for (int t = 0; t < 16; ++t) {
    float qs = query[h*32 + 2*t] + query[h*32 + 2*t + 1];
    acc += qs * We[(16*h + t)*16 + k];
  }
  Qe[h*16 + k] = acc;
  if (k == 0) {
    float accb = 0.f;
    for (int t = 0; t < 16; ++t) {
      float qs = query[h*32 + 2*t] + query[h*32 + 2*t + 1];
      accb += qs * be[16*h + t];
    }
    cb[h] = accb;
  }
}

// K1: hidden = x @ W^T + b, fused A[n,h], B[n,h] head-projections.
// Register-tiled SGEMM: 64 rows/block, 256 threads, each thread owns a 4x4
// output tile (rows trg*4.., cols tc*4..). Both operands staged in LDS:
//   xs[r][k]  : 64x128 fp32, XOR-swizzled  k ^ ((r&7)<<2)  -> b128 reads 2-way
//   wt[k][c]  : 128x64 fp32, XOR-swizzled  c ^ ((k&7)<<2)  -> b128 reads 2-way
// Inner loop per 4-k: 8 ds_read_b128 : 64 v_fmac (load-pipe demand ~8x lower
// than the old wave-uniform global-broadcast version, which was latency-bound
// at 31% VALUBusy / 5% HBM). LDS = 32KB + 32KB = 64KB -> 2 blocks/CU.
#define BM 64

__global__ __launch_bounds__(256) void hidden_ab(
    const float* __restrict__ x, const float* __restrict__ W,
    const float* __restrict__ b, const float* __restrict__ query,
    float* __restrict__ hidden, float* __restrict__ Av, float* __restrict__ Bv, int N) {
  __shared__ float wt[128 * 64];   // wt[k*64 + (c ^ ((k&7)<<2))]
  __shared__ float xs[BM * 128];   // xs[r*128 + (k ^ ((r&7)<<2))]
  int t = threadIdx.x;
  int rowbase = blockIdx.x * BM;

  // stage W (32KB, L2-hot): coalesced read W[c][k], swizzled write wt[k][c]
#pragma unroll
  for (int i = 0; i < 32; ++i) {
    int idx = t + 256 * i;            // 0..8191 over flat W[c*128+k]
    int c = idx >> 7, k = idx & 127;
    wt[k * 64 + (c ^ ((k & 7) << 2))] = W[idx];
  }
  // stage x tile (32KB): coalesced float4 read, swizzled b128 write
#pragma unroll
  for (int i = 0; i < 8; ++i) {
    int idx4 = t + 256 * i;           // 0..2047 float4s (64 rows x 32)
    int r = idx4 >> 5, kc4 = idx4 & 31;
    int row = rowbase + r;
    float4 v = (row < N) ? ((const float4*)x)[(size_t)row * 32 + kc4]
                         : make_float4(0.f, 0.f, 0.f, 0.f);
    *(float4*)&xs[r * 128 + ((kc4 * 4) ^ ((r & 7) << 2))] = v;
  }
  __syncthreads();

  int tc = t & 15;            // col group: cols tc*4..tc*4+3
  int trg = t >> 4;           // row group: local rows trg*4..trg*4+3
  int c0 = tc * 4;
  const float* xb0 = &xs[(trg * 4 + 0) * 128];
  const float* xb1 = &xs[(trg * 4 + 1) * 128];
  const float* xb2 = &xs[(trg * 4 + 2) * 128];
  const float* xb3 = &xs[(trg * 4 + 3) * 128];
  const int sx0 = ((trg * 4 + 0) & 7) << 2;
  const int sx1 = ((trg * 4 + 1) & 7) << 2;
  const int sx2 = ((trg * 4 + 2) & 7) << 2;
  const int sx3 = ((trg * 4 + 3) & 7) << 2;

  float acc[4][4];
#pragma unroll
  for (int i = 0; i < 4; ++i)
#pragma unroll
    for (int j = 0; j < 4; ++j) acc[i][j] = 0.f;

#define ACCROW(i, XA) \
  acc[i][0] += (XA).x*wb0.x + (XA).y*wb1.x + (XA).z*wb2.x + (XA).w*wb3.x; \
  acc[i][1] += (XA).x*wb0.y + (XA).y*wb1.y + (XA).z*wb2.y + (XA).w*wb3.y; \
  acc[i][2] += (XA).x*wb0.z + (XA).y*wb1.z + (XA).z*wb2.z + (XA).w*wb3.z; \
  acc[i][3] += (XA).x*wb0.w + (XA).y*wb1.w + (XA).z*wb2.w + (XA).w*wb3.w;

#pragma unroll 2
  for (int k = 0; k < 128; k += 4) {
    float4 xa0 = *(const float4*)(xb0 + (k ^ sx0));
    float4 xa1 = *(const float4*)(xb1 + (k ^ sx1));
    float4 xa2 = *(const float4*)(xb2 + (k ^ sx2));
    float4 xa3 = *(const float4*)(xb3 + (k ^ sx3));
    float4 wb0 = *(const float4*)&wt[(k + 0) * 64 + (c0 ^ (((k + 0) & 7) << 2))];
    float4 wb1 = *(const float4*)&wt[(k + 1) * 64 + (c0 ^ (((k + 1) & 7) << 2))];
    float4 wb2 = *(const float4*)&wt[(k + 2) * 64 + (c0 ^ (((k + 2) & 7) << 2))];
    float4 wb3 = *(const float4*)&wt[(k + 3) * 64 + (c0 ^ (((k + 3) & 7) << 2))];
    ACCROW(0, xa0)
    ACCROW(1, xa1)
    ACCROW(2, xa2)
    ACCROW(3, xa3)
  }
#undef ACCROW

  // epilogue: bias, store hidden, fused per-head query projections
  float4 bv4 = ((const float4*)b)[tc];
  int h = tc >> 2;
  float qa[4], qb[4];
#pragma unroll
  for (int j = 0; j < 4; ++j) {
    int tt = (tc & 3) * 4 + j;
    qa[j] = query[h * 32 + 2 * tt];
    qb[j] = query[h * 32 + 2 * tt + 1];
  }
  float pa[4], pb[4];
#pragma unroll
  for (int i = 0; i < 4; ++i) {
    int row = rowbase + trg * 4 + i;
    float4 v;
    v.x = acc[i][0] + bv4.x; v.y = acc[i][1] + bv4.y;
    v.z = acc[i][2] + bv4.z; v.w = acc[i][3] + bv4.w;
    if (row < N) *(float4*)(hidden + (size_t)row * 64 + c0) = v;
    pa[i] = qa[0]*v.x + qa[1]*v.y + qa[2]*v.z + qa[3]*v.w;
    pb[i] = qb[0]*v.x + qb[1]*v.y + qb[2]*v.z + qb[3]*v.w;
  }
  // reduce over the 4 lanes sharing (trg, head): lanes differ in bits 0..1
#pragma unroll
  for (int mask = 1; mask <= 2; mask <<= 1) {
#pragma unroll
    for (int i = 0; i < 4; ++i) {
      pa[i] += __shfl_xor(pa[i], mask);
      pb[i] += __shfl_xor(pb[i], mask);
    }
  }
  if ((tc & 3) == 0) {
#pragma unroll
    for (int i = 0; i < 4; ++i) {
      int row = rowbase + trg * 4 + i;
      if (row < N) {
        Av[(size_t)row * 4 + h] = pa[i];
        Bv[(size_t)row * 4 + h] = pb[i];
      }
    }
  }
}

// K2: 8-way partitioned in-degree histogram. Partition = blockIdx.x & 7.
// MUST use the same grid/block shape as edge_rec so edge m maps to the same
// partition in both passes.
__global__ __launch_bounds__(256) void count_deg8(
    const int* __restrict__ el, unsigned* __restrict__ counts8, int E, int N) {
  int m = blockIdx.x * 256 + threadIdx.x;
  if (m >= E) return;
  int2 e2 = ((const int2*)el)[m];
  atomicAdd(counts8 + (size_t)(blockIdx.x & (NPART - 1)) * N + e2.y, 1u);
}

// ---- scan of per-node totals -> row_ptr[N+1] and 8 per-partition cursors ----
#define SCAN_CHUNK 2048

__global__ __launch_bounds__(256) void scan_reduce(
    const unsigned* __restrict__ counts8, unsigned* __restrict__ partial, int N) {
  __shared__ unsigned ssum[256];
  int t = threadIdx.x;
  int base = blockIdx.x * SCAN_CHUNK + t * 8;
  unsigned local = 0;
#pragma unroll
  for (int k = 0; k < 8; ++k) {
    int i = base + k;
    if (i < N) {
      unsigned tot = 0;
#pragma unroll
      for (int p = 0; p < NPART; ++p) tot += counts8[(size_t)p * N + i];
      local += tot;
    }
  }
  ssum[t] = local; __syncthreads();
  for (int off = 128; off > 0; off >>= 1) {
    if (t < off) ssum[t] += ssum[t + off];
    __syncthreads();
  }
  if (t == 0) partial[blockIdx.x] = ssum[0];
}

__global__ void scan_partials(unsigned* __restrict__ partial, int nb) {
  if (threadIdx.x == 0) {
    unsigned run = 0;
    for (int i = 0; i < nb; ++i) { unsigned v = partial[i]; partial[i] = run; run += v; }
  }
}

__global__ __launch_bounds__(256) void scan_scatter(
    const unsigned* __restrict__ counts8, const unsigned* __restrict__ partial,
    unsigned* __restrict__ row_ptr, unsigned* __restrict__ cursor8, int N, int E) {
  __shared__ unsigned ssum[256];
  int t = threadIdx.x;
  int base = blockIdx.x * SCAN_CHUNK + t * 8;
  unsigned tot[8]; unsigned local = 0;
#pragma unroll
  for (int k = 0; k < 8; ++k) {
    int i = base + k;
    unsigned s = 0;
    if (i < N) {
#pragma unroll
      for (int p = 0; p < NPART; ++p) s += counts8[(size_t)p * N + i];
    }
    tot[k] = s; local += s;
  }
  ssum[t] = local; __syncthreads();
  for (int off = 1; off < 256; off <<= 1) {
    unsigned add = (t >= off) ? ssum[t - off] : 0u;
    __syncthreads();
    ssum[t] += add;
    __syncthreads();
  }
  unsigned run = partial[blockIdx.x] + (t ? ssum[t - 1] : 0u);
#pragma unroll
  for (int k = 0; k < 8; ++k) {
    int i = base + k;
    if (i < N) {
      row_ptr[i] = run;
      unsigned pref = run;
#pragma unroll
      for (int p = 0; p < NPART; ++p) {
        cursor8[(size_t)p * N + i] = pref;
        pref += counts8[(size_t)p * N + i];
      }
      run += tot[k];
    }
  }
  if (blockIdx.x == 0 && t == 0) row_ptr[N] = (unsigned)E;
}

// K3: edge-parallel attention-weight records. Per edge: logits from streamed ef
// + L2-resident Av/Bv gathers, aa_h = exp(leaky(w))*ew as fp16x4, one aligned
// 16B scattered store {nin, aa01, aa23, 0} into the CSR slot claimed from the
// partitioned cursor.
__global__ __launch_bounds__(256) void edge_rec(
    const int* __restrict__ el, const float* __restrict__ ew_arr,
    const float* __restrict__ ef,
    const float* __restrict__ Av, const float* __restrict__ Bv,
    const float* __restrict__ Qe, const float* __restrict__ cb,
    unsigned* __restrict__ cursor8, float4* __restrict__ rec, int E, int N) {
  int m = blockIdx.x * 256 + threadIdx.x;
  if (m >= E) return;
  int2 e2 = ((const int2*)el)[m];
  const float4* ef4 = (const float4*)(ef + (size_t)m * 16);
  float4 f0 = ef4[0], f1 = ef4[1], f2 = ef4[2], f3 = ef4[3];
  const float4* q4 = (const float4*)Qe;
  float w0, w1, w2, w3;
  {
    float4 q;
    q = q4[0];  w0  = DOT4(f0, q);  q = q4[1];  w0 += DOT4(f1, q);
    q = q4[2];  w0 += DOT4(f2, q);  q = q4[3];  w0 += DOT4(f3, q);
    q = q4[4];  w1  = DOT4(f0, q);  q = q4[5];  w1 += DOT4(f1, q);
    q = q4[6];  w1 += DOT4(f2, q);  q = q4[7];  w1 += DOT4(f3, q);
    q = q4[8];  w2  = DOT4(f0, q);  q = q4[9];  w2 += DOT4(f1, q);
    q = q4[10]; w2 += DOT4(f2, q);  q = q4[11]; w2 += DOT4(f3, q);
    q = q4[12]; w3  = DOT4(f0, q);  q = q4[13]; w3 += DOT4(f1, q);
    q = q4[14]; w3 += DOT4(f2, q);  q = q4[15]; w3 += DOT4(f3, q);
  }
  float4 av = ((const float4*)Av)[e2.x];
  float4 bv = ((const float4*)Bv)[e2.y];
  w0 += av.x + bv.x + cb[0];
  w1 += av.y + bv.y + cb[1];
  w2 += av.z + bv.z + cb[2];
  w3 += av.w + bv.w + cb[3];
  w0 = w0 > 0.f ? w0 : SLOPE * w0;
  w1 = w1 > 0.f ? w1 : SLOPE * w1;
  w2 = w2 > 0.f ? w2 : SLOPE * w2;
  w3 = w3 > 0.f ? w3 : SLOPE * w3;
  float ew = ew_arr[m];
  float a0 = __expf(w0) * ew, a1 = __expf(w1) * ew;
  float a2 = __expf(w2) * ew, a3 = __expf(w3) * ew;
  unsigned pos = atomicAdd(cursor8 + (size_t)(blockIdx.x & (NPART - 1)) * N + e2.y, 1u);
  float4 r;
  r.x = __int_as_float(e2.x);
  r.y = h2_as_float(__floats2half2_rn(a0, a1));
  r.z = h2_as_float(__floats2half2_rn(a2, a3));
  r.w = 0.f;
  rec[pos] = r;
}

// K4: per-node gather, 4 edges per wave iteration, float4 hidden loads.
// lane = g*16 + j; group g handles edges base+g; lane j covers features 4j..4j+3
// (all in head h = j>>2). Self-loop handled by group 0. Butterfly over masks
// {16,32} sums groups; group 0 stores the row.
__global__ __launch_bounds__(256) void gather_rec(
    const unsigned* __restrict__ row_ptr, const float4* __restrict__ rec,
    const float* __restrict__ Av, const float* __restrict__ Bv,
    const float* __restrict__ hidden, float* __restrict__ out, int N) {
  int n = (blockIdx.x * 256 + threadIdx.x) >> 6;
  if (n >= N) return;
  int lane = threadIdx.x & 63;
  int g = lane >> 4, j = lane & 15, h = j >> 2;
  unsigned i0 = row_ptr[n], i1 = row_ptr[n + 1];
  float4 acc = make_float4(0.f, 0.f, 0.f, 0.f);
  float nsum = 0.f;

  // self-loop: aa = exp(leaky(A[n,h]+B[n,h])), group 0 only
  if (g == 0) {
    float4 av = ((const float4*)Av)[n];
    float4 bv = ((const float4*)Bv)[n];
    float avh = (h == 0) ? av.x : (h == 1) ? av.y : (h == 2) ? av.z : av.w;
    float bvh = (h == 0) ? bv.x : (h == 1) ? bv.y : (h == 2) ? bv.z : bv.w;
    float w = avh + bvh;
    w = w > 0.f ? w : SLOPE * w;
    float aas = __expf(w);
    nsum = aas;
    float4 hv = *(const float4*)(hidden + (size_t)n * 64 + 4 * j);
    acc.x = aas * hv.x; acc.y = aas * hv.y; acc.z = aas * hv.z; acc.w = aas * hv.w;
  }

  // 2-stage pipelined 4-edge loop
  unsigned idx = i0 + g;
  float4 r_cur = (idx < i1) ? rec[idx] : make_float4(0.f, 0.f, 0.f, 0.f);
  for (unsigned base = i0; base < i1; base += 4) {
    unsigned nidx = base + 4 + g;
    float4 r_nxt = (nidx < i1) ? rec[nidx] : make_float4(0.f, 0.f, 0.f, 0.f);
    int nin = __float_as_int(r_cur.x);
    __half2 aa01 = float_as_h2(r_cur.y);
    __half2 aa23 = float_as_h2(r_cur.z);
    float aa = (h == 0) ? __low2float(aa01) : (h == 1) ? __high2float(aa01)
             : (h == 2) ? __low2float(aa23) : __high2float(aa23);
    float4 hv = *(const float4*)(hidden + (size_t)nin * 64 + 4 * j);
    nsum += aa;
    acc.x += aa * hv.x; acc.y += aa * hv.y; acc.z += aa * hv.z; acc.w += aa * hv.w;
    r_cur = r_nxt;
  }

  // reduce across the 4 groups (lanes j, j+16, j+32, j+48)
#pragma unroll
  for (int mask = 16; mask <= 32; mask <<= 1) {
    acc.x += __shfl_xor(acc.x, mask);
    acc.y += __shfl_xor(acc.y, mask);
    acc.z += __shfl_xor(acc.z, mask);
    acc.w += __shfl_xor(acc.w, mask);
    nsum  += __shfl_xor(nsum, mask);
  }
  if (g == 0) {
    float c = (float)(i1 - i0 + 1u);
    float F = 1.f / ((nsum / c + EPSV) * c);
    float4 v;
    v.x = acc.x * F; v.y = acc.y * F; v.z = acc.z * F; v.w = acc.w * F;
    v.x = v.x > 0.f ? v.x : 0.f;
    v.y = v.y > 0.f ? v.y : 0.f;
    v.z = v.z > 0.f ? v.z : 0.f;
    v.w = v.w > 0.f ? v.w : 0.f;
    *(float4*)(out + (size_t)n * 64 + 4 * j) = v;
  }
}

extern "C" void kernel_launch(void* const* d_in, const int* in_sizes, int n_in,
                              void* d_out, int out_size, void* d_ws, size_t ws_size,
                              hipStream_t stream) {
  const int*   el = (const int*)d_in[0];
  const float* ew = (const float*)d_in[1];
  const float* ef = (const float*)d_in[2];
  const float* x  = (const float*)d_in[4];
  const float* W  = (const float*)d_in[5];
  const float* b  = (const float*)d_in[6];
  const float* We = (const float*)d_in[7];
  const float* be = (const float*)d_in[8];
  const float* q  = (const float*)d_in[9];
  int E = in_sizes[0] / 2;
  int N = in_sizes[4] / 128;

  float* ws = (float*)d_ws;
  size_t off = 0;
  float* hidden = ws + off; off += (size_t)N * 64;
  float4* rec   = (float4*)(ws + off); off += (size_t)E * 4 + 16;
  float* Av     = ws + off; off += (size_t)N * 4;
  float* Bv     = ws + off; off += (size_t)N * 4;
  unsigned* counts8 = (unsigned*)(ws + off); off += (size_t)N * NPART;
  unsigned* cursor8 = (unsigned*)(ws + off); off += (size_t)N * NPART;
  unsigned* row_ptr = (unsigned*)(ws + off); off += (size_t)N + 16;
  unsigned* partial = (unsigned*)(ws + off); off += 64;
  float* Qe     = ws + off; off += 64;
  float* cb     = ws + off; off += 4;
  float* outp   = (float*)d_out;

  hipMemsetAsync(counts8, 0, (size_t)N * NPART * sizeof(unsigned), stream);

  int nb = (N + SCAN_CHUNK - 1) / SCAN_CHUNK;   // 49 for N=100k
  int eb = (E + 255) / 256;

  prep_qe<<<1, 64, 0, stream>>>(We, be, q, Qe, cb);
  hidden_ab<<<(N + BM - 1) / BM, 256, 0, stream>>>(x, W, b, q, hidden, Av, Bv, N);
  count_deg8<<<eb, 256, 0, stream>>>(el, counts8, E, N);
  scan_reduce<<<nb, 256, 0, stream>>>(counts8, partial, N);
  scan_partials<<<1, 64, 0, stream>>>(partial, nb);
  scan_scatter<<<nb, 256, 0, stream>>>(counts8, partial, row_ptr, cursor8, N, E);
  edge_rec<<<eb, 256, 0, stream>>>(el, ew, ef, Av, Bv, Qe, cb, cursor8, rec, E, N);
  gather_rec<<<(N * 64 + 255) / 256, 256, 0, stream>>>(row_ptr, rec, Av, Bv,
                                                       hidden, outp, N);
}